// Round 15
// baseline (3444.307 us; speedup 1.0000x reference)
//
#include <hip/hip_runtime.h>
#include <hip/hip_cooperative_groups.h>
#include <hip/hip_bf16.h>
#include <math.h>

namespace cgx = cooperative_groups;

static constexpr int NCOIL = 12;
static constexpr int HWSZ  = 65536;   // 256*256

typedef short v8s __attribute__((ext_vector_type(8)));
typedef float v4f __attribute__((ext_vector_type(4)));

__device__ __forceinline__ unsigned short f2bf(float v) {
  __hip_bfloat16 h = __float2bfloat16(v);
  union { __hip_bfloat16 h; unsigned short u; } cv; cv.h = h; return cv.u;
}
__device__ __forceinline__ float bf2f(unsigned short u) {
  return __uint_as_float(((unsigned)u) << 16);
}
__device__ __forceinline__ unsigned pack_bf(float2 v) {
  return ((unsigned)f2bf(v.y) << 16) | (unsigned)f2bf(v.x);
}
__device__ __forceinline__ float2 unpack_bf(unsigned u) {
  return make_float2(bf2f((unsigned short)(u & 0xffffu)),
                     bf2f((unsigned short)(u >> 16)));
}

// ---------------- complex helpers ----------------
__device__ __forceinline__ float2 cmulf(float2 a, float2 b) {
  return make_float2(a.x * b.x - a.y * b.y, a.x * b.y + a.y * b.x);
}
__device__ __forceinline__ float2 caddf(float2 a, float2 b) {
  return make_float2(a.x + b.x, a.y + b.y);
}
__device__ __forceinline__ float2 csubf(float2 a, float2 b) {
  return make_float2(a.x - b.x, a.y - b.y);
}

// ---------------- block reductions ----------------
__device__ __forceinline__ float blockRed256(float v, float* sm) {
  #pragma unroll
  for (int off = 32; off; off >>= 1) v += __shfl_down(v, off);
  int lane = threadIdx.x & 63, wv = threadIdx.x >> 6;
  if (lane == 0) sm[wv] = v;
  __syncthreads();
  return sm[0] + sm[1] + sm[2] + sm[3];
}

__device__ __forceinline__ void blockRed2(float& a, float& b, float2* sm) {
  #pragma unroll
  for (int off = 32; off; off >>= 1) {
    a += __shfl_down(a, off);
    b += __shfl_down(b, off);
  }
  int lane = threadIdx.x & 63, wv = threadIdx.x >> 6;
  if (lane == 0) sm[wv] = make_float2(a, b);
  __syncthreads();
  float2 s0 = sm[0], s1 = sm[1], s2 = sm[2], s3 = sm[3];
  a = s0.x + s1.x + s2.x + s3.x;
  b = s0.y + s1.y + s2.y + s3.y;
}

// ---------------- in-register 16-pt DFT ----------------
__device__ __constant__ const float TC16[8] = {
  1.f, 0.92387953f, 0.70710678f, 0.38268343f, 0.f, -0.38268343f, -0.70710678f, -0.92387953f};
__device__ __constant__ const float TS16[8] = {
  0.f, -0.38268343f, -0.70710678f, -0.92387953f, -1.f, -0.92387953f, -0.70710678f, -0.38268343f};
__device__ __constant__ const int REV4[16] = {0,8,4,12,2,10,6,14,1,9,5,13,3,11,7,15};

template<int INV>
__device__ __forceinline__ void dif16(float2 v[16]) {
  #pragma unroll
  for (int ls = 0; ls < 4; ++ls) {
    const int len = 16 >> ls, half = len >> 1, step = 1 << ls;
    #pragma unroll
    for (int i = 0; i < 16; i += len) {
      #pragma unroll
      for (int j = 0; j < half; ++j) {
        float2 a = v[i + j], b = v[i + j + half];
        v[i + j] = caddf(a, b);
        float2 d = csubf(a, b);
        float cr = TC16[j * step];
        float ci = INV ? -TS16[j * step] : TS16[j * step];
        v[i + j + half] = make_float2(d.x * cr - d.y * ci, d.x * ci + d.y * cr);
      }
    }
  }
}

template<int INV>
__device__ __forceinline__ void dit16(float2 v[16]) {
  #pragma unroll
  for (int ls = 0; ls < 4; ++ls) {
    const int len = 2 << ls, half = len >> 1, step = 16 / len;
    #pragma unroll
    for (int i = 0; i < 16; i += len) {
      #pragma unroll
      for (int j = 0; j < half; ++j) {
        float cr = TC16[j * step];
        float ci = INV ? -TS16[j * step] : TS16[j * step];
        float2 b = v[i + j + half];
        float2 tt = make_float2(b.x * cr - b.y * ci, b.x * ci + b.y * cr);
        float2 a = v[i + j];
        v[i + j] = caddf(a, tt);
        v[i + j + half] = csubf(a, tt);
      }
    }
  }
}

// ---------------- merged prep kernel ----------------
__global__ __launch_bounds__(256) void k_prep(
    const float* __restrict__ w1, const float* __restrict__ w2,
    const float* __restrict__ w3, const float* __restrict__ w4,
    const float* __restrict__ w5, const float* __restrict__ csm_r,
    const float* __restrict__ csm_i,
    float* __restrict__ w1T, unsigned short* __restrict__ bf2,
    unsigned short* __restrict__ bf3, unsigned short* __restrict__ bf4,
    unsigned short* __restrict__ bf5, unsigned* __restrict__ csmh,
    float2* __restrict__ twf)
{
  const int bx = blockIdx.x;
  const int t = threadIdx.x;
  if (bx < 24576) {
    int i = bx * 256 + t;
    csmh[i] = ((unsigned)f2bf(csm_i[i]) << 16) | (unsigned)f2bf(csm_r[i]);
    return;
  }
  int r = bx - 24576;
  if (r < 432) {
    const float* w = (r < 144) ? w2 : (r < 288) ? w3 : w4;
    unsigned short* bf = (r < 144) ? bf2 : (r < 288) ? bf3 : bf4;
    int i = (r % 144) * 256 + t;
    int j = i & 7, lane = (i >> 3) & 63, ocg = (i >> 9) & 3, ks = i >> 11;
    int oc = (ocg << 4) + (lane & 15);
    int ic = ((ks & 1) << 5) + (((lane >> 4) & 3) << 3) + j;
    bf[i] = f2bf(w[(oc * 64 + ic) * 9 + (ks >> 1)]);
    return;
  }
  r -= 432;
  if (r < 36) {
    int i = r * 256 + t;
    int j = i & 7, lane = (i >> 3) & 63, ks = i >> 9;
    int oc = lane & 15;
    int ic = ((ks & 1) << 5) + (((lane >> 4) & 3) << 3) + j;
    bf5[i] = (oc < 2) ? f2bf(w5[(oc * 64 + ic) * 9 + (ks >> 1)]) : (unsigned short)0;
    return;
  }
  r -= 36;
  if (r < 5) {
    int i = r * 256 + t;
    if (i < 1152) {
      int oc = i & 63;
      int rest = i >> 6;            // ic*9+k
      int ic = rest / 9, k = rest - ic * 9;
      w1T[i] = w1[(oc * 2 + ic) * 9 + k];
    }
    return;
  }
  float ang = -6.28318530717958647692f * (float)t / 256.f;
  float s, c; sincosf(ang, &s, &c);
  twf[t] = make_float2(c, s);
}

// ---------------- layer 1: fp32 direct conv (IC=2), out pixel-major bf16 ----------------
__global__ __launch_bounds__(256) void k_conv1(
    const float* __restrict__ atb,
    const float* __restrict__ w1T,
    const float* __restrict__ b1,
    unsigned short* __restrict__ out)
{
  __shared__ float patch[2 * 324];
  const int t = threadIdx.x;
  const int img = blockIdx.z;
  const float* in = atb + (size_t)img * 131072;
  const int tx0 = blockIdx.x << 4, ty0 = blockIdx.y << 4;
  for (int i = t; i < 648; i += 256) {
    int ic = i / 324, rem = i - ic * 324;
    int py = rem / 18, px = rem - py * 18;
    int gy = ty0 + py - 1, gx = tx0 + px - 1;
    float v = 0.f;
    if ((unsigned)gy < 256u && (unsigned)gx < 256u)
      v = in[(ic << 16) + (gy << 8) + gx];
    patch[i] = v;
  }
  __syncthreads();
  const int tx = t & 15, ty = t >> 4;
  float acc[64];
  #pragma unroll
  for (int o = 0; o < 64; ++o) acc[o] = 0.f;
  #pragma unroll
  for (int ic = 0; ic < 2; ++ic) {
    const float* pb = &patch[ic * 324 + ty * 18 + tx];
    #pragma unroll
    for (int k = 0; k < 9; ++k) {
      const float v = pb[(k / 3) * 18 + (k % 3)];
      const float* wr = &w1T[(ic * 9 + k) << 6];
      #pragma unroll
      for (int o = 0; o < 64; ++o) acc[o] = fmaf(v, wr[o], acc[o]);
    }
  }
  size_t obase = ((size_t)img << 22) + ((size_t)(((ty0 + ty) << 8) + tx0 + tx) << 6);
  v8s* outv = (v8s*)(out + obase);
  #pragma unroll
  for (int g = 0; g < 8; ++g) {
    v8s ov;
    #pragma unroll
    for (int j = 0; j < 8; ++j) {
      float v = fmaxf(acc[(g << 3) + j] + b1[(g << 3) + j], 0.f);
      ov[j] = (short)f2bf(v);
    }
    outv[g] = ov;
  }
}

// ---- layers 2-4: bf16 MFMA implicit GEMM, 16x16 tile, 4 waves x (4 rows x 64 oc) ----
__global__ __launch_bounds__(256, 3) void k_conv_mfma(
    const unsigned short* __restrict__ in,
    const unsigned short* __restrict__ bfrag,
    const float* __restrict__ bias,
    unsigned short* __restrict__ out)
{
  __shared__ v8s halo[2592];   // 41472 B
  __shared__ v8s bsh[768];     // 12288 B
  char* hb = (char*)halo;
  const int t = threadIdx.x;
  const int img = blockIdx.z;
  const int tx0 = blockIdx.x << 4, ty0 = blockIdx.y << 4;
  const size_t ibase = ((size_t)img << 22);
  for (int c = t; c < 2592; c += 256) {
    int hy = c / 144, rem = c - hy * 144;
    int hx = rem >> 3, slot = rem & 7;
    int gy = ty0 + hy - 1, gx = tx0 + hx - 1;
    v8s v = {0, 0, 0, 0, 0, 0, 0, 0};
    if ((unsigned)gy < 256u && (unsigned)gx < 256u)
      v = *(const v8s*)(in + ibase + ((size_t)((gy << 8) + gx) << 6) + (slot << 3));
    int xl = hy * 18 + hx;
    *(v8s*)(hb + xl * 128 + ((slot ^ (xl & 7)) << 4)) = v;
  }
  const v8s* bg = (const v8s*)bfrag;
  v8s breg[3];
  #pragma unroll
  for (int i = 0; i < 3; ++i) breg[i] = bg[t + (i << 8)];
  #pragma unroll
  for (int i = 0; i < 3; ++i) bsh[t + (i << 8)] = breg[i];
  #pragma unroll
  for (int i = 0; i < 3; ++i) breg[i] = bg[768 + t + (i << 8)];
  __syncthreads();

  const int lane = t & 63, w = t >> 6;
  const int px = lane & 15, lg = lane >> 4;
  v4f acc[4][4];
  #pragma unroll
  for (int pf = 0; pf < 4; ++pf)
    #pragma unroll
    for (int og = 0; og < 4; ++og)
      #pragma unroll
      for (int rg = 0; rg < 4; ++rg) acc[pf][og][rg] = 0.f;

  #pragma unroll
  for (int chunk = 0; chunk < 6; ++chunk) {
    #pragma unroll
    for (int k3 = 0; k3 < 3; ++k3) {
      const int ks = chunk * 3 + k3;
      const int tap = ks >> 1;
      const int dy = tap / 3, dx = tap - dy * 3;
      const int slot = ((ks & 1) << 2) | lg;
      v8s b0 = bsh[((k3 << 2) | 0) * 64 + lane];
      v8s b1 = bsh[((k3 << 2) | 1) * 64 + lane];
      v8s b2 = bsh[((k3 << 2) | 2) * 64 + lane];
      v8s b3 = bsh[((k3 << 2) | 3) * 64 + lane];
      #pragma unroll
      for (int pf = 0; pf < 4; ++pf) {
        int xl = (w * 4 + pf + dy) * 18 + px + dx;
        v8s a = *(const v8s*)(hb + xl * 128 + ((slot ^ (xl & 7)) << 4));
        acc[pf][0] = __builtin_amdgcn_mfma_f32_16x16x32_bf16(a, b0, acc[pf][0], 0, 0, 0);
        acc[pf][1] = __builtin_amdgcn_mfma_f32_16x16x32_bf16(a, b1, acc[pf][1], 0, 0, 0);
        acc[pf][2] = __builtin_amdgcn_mfma_f32_16x16x32_bf16(a, b2, acc[pf][2], 0, 0, 0);
        acc[pf][3] = __builtin_amdgcn_mfma_f32_16x16x32_bf16(a, b3, acc[pf][3], 0, 0, 0);
      }
    }
    if (chunk < 5) {
      __syncthreads();
      #pragma unroll
      for (int i = 0; i < 3; ++i) bsh[t + (i << 8)] = breg[i];
      if (chunk < 4) {
        #pragma unroll
        for (int i = 0; i < 3; ++i) breg[i] = bg[(chunk + 2) * 768 + t + (i << 8)];
      }
      __syncthreads();
    }
  }
  const int ocl = lane & 15;
  float bv[4];
  #pragma unroll
  for (int og = 0; og < 4; ++og) bv[og] = bias[(og << 4) + ocl];
  #pragma unroll
  for (int pf = 0; pf < 4; ++pf) {
    const int gy = ty0 + (w << 2) + pf;
    #pragma unroll
    for (int og = 0; og < 4; ++og) {
      const int oc = (og << 4) + ocl;
      #pragma unroll
      for (int rg = 0; rg < 4; ++rg) {
        float v = fmaxf(acc[pf][og][rg] + bv[og], 0.f);
        int gx = tx0 + (lg << 2) + rg;
        out[ibase + ((size_t)((gy << 8) + gx) << 6) + oc] = f2bf(v);
      }
    }
  }
}

// ---------------- layer 5 (64->2, MFMA) + rhs ----------------
__global__ __launch_bounds__(512, 4) void k_conv5_rhs(
    const unsigned short* __restrict__ in,
    const unsigned short* __restrict__ bf5,
    const float* __restrict__ b5,
    const float* __restrict__ atb,
    const float* __restrict__ lam,
    float2* __restrict__ rhs)
{
  __shared__ v8s halo[2592];
  char* hb = (char*)halo;
  const int t = threadIdx.x;
  const int img = blockIdx.z;
  const int tx0 = blockIdx.x << 4, ty0 = blockIdx.y << 4;
  const size_t ibase = ((size_t)img << 22);
  for (int c = t; c < 2592; c += 512) {
    int hy = c / 144, rem = c - hy * 144;
    int hx = rem >> 3, slot = rem & 7;
    int gy = ty0 + hy - 1, gx = tx0 + hx - 1;
    v8s v = {0, 0, 0, 0, 0, 0, 0, 0};
    if ((unsigned)gy < 256u && (unsigned)gx < 256u)
      v = *(const v8s*)(in + ibase + ((size_t)((gy << 8) + gx) << 6) + (slot << 3));
    int xl = hy * 18 + hx;
    *(v8s*)(hb + xl * 128 + ((slot ^ (xl & 7)) << 4)) = v;
  }
  __syncthreads();
  const int lane = t & 63, w = t >> 6;
  const int px = lane & 15, lg = lane >> 4;
  v4f acc[2];
  #pragma unroll
  for (int pf = 0; pf < 2; ++pf)
    #pragma unroll
    for (int rg = 0; rg < 4; ++rg) acc[pf][rg] = 0.f;
  #pragma unroll
  for (int ks = 0; ks < 18; ++ks) {
    const int tap = ks >> 1;
    const int dy = tap / 3, dx = tap - dy * 3;
    const int slot = ((ks & 1) << 2) | lg;
    v8s b = *(const v8s*)(bf5 + (((ks * 64) + lane) << 3));
    #pragma unroll
    for (int pf = 0; pf < 2; ++pf) {
      int xl = (w * 2 + pf + dy) * 18 + px + dx;
      v8s a = *(const v8s*)(hb + xl * 128 + ((slot ^ (xl & 7)) << 4));
      acc[pf] = __builtin_amdgcn_mfma_f32_16x16x32_bf16(a, b, acc[pf], 0, 0, 0);
    }
  }
  const int ocl = lane & 15;
  const float l = *lam;
  const float bsel = b5[ocl & 1];
  #pragma unroll
  for (int pf = 0; pf < 2; ++pf) {
    const int gy = ty0 + w * 2 + pf;
    #pragma unroll
    for (int rg = 0; rg < 4; ++rg) {
      float v = acc[pf][rg] + bsel;
      float d1 = __shfl_down(v, 1);
      if (ocl == 0) {
        int gx = tx0 + (lg << 2) + rg;
        int pix = (gy << 8) + gx;
        float x0 = atb[(size_t)img * 131072 + pix];
        float x1 = atb[(size_t)img * 131072 + 65536 + pix];
        rhs[(size_t)img * 65536 + pix] =
            make_float2(fmaf(l, x0 + v, x0), fmaf(l, x1 + d1, x1));
      }
    }
  }
}

// ================= FALLBACK CG kernels (round-13 proven) =================
__global__ __launch_bounds__(256, 3) void k_coil_fft_rows(
    const float2* __restrict__ p_prev, const float2* __restrict__ r,
    float2* __restrict__ p_out,
    const float* __restrict__ part_r_old, const float* __restrict__ part_r_new,
    const int first,
    const unsigned* __restrict__ csmh, const float2* __restrict__ twf,
    unsigned* __restrict__ coil, float* __restrict__ part_p)
{
  __shared__ float2 trans[4096];
  __shared__ float2 sm2[4];
  __shared__ float sm1[4];
  const int t = threadIdx.x;
  const int b = blockIdx.x, cs = blockIdx.z;
  const int idx = t & 15, row16 = t >> 4;
  const int row = (blockIdx.y << 4) + row16;

  float beta = 0.f; bool do_upd = false;
  if (!first) {
    float so = 0.f, sn = 0.f;
    for (int i = t; i < 512; i += 256) { so += part_r_old[i]; sn += part_r_new[i]; }
    blockRed2(so, sn, sm2);
    do_upd = so > 1e-10f;
    beta = do_upd ? sn / so : 0.f;
  }
  const int pb = (b << 16) + (row << 8);
  float2 pv[16];
  float pe = 0.f;
  #pragma unroll
  for (int h2 = 0; h2 < 16; ++h2) {
    int n = idx + (h2 << 4);
    float2 t0 = p_prev[pb + n];
    if (!first && do_upd) {
      float2 rv = r[pb + n];
      t0 = make_float2(fmaf(beta, t0.x, rv.x), fmaf(beta, t0.y, rv.y));
    }
    pv[h2] = t0;
    if (cs == 0) {
      if (!first) p_out[pb + n] = t0;
      pe = fmaf(t0.x, t0.x, fmaf(t0.y, t0.y, pe));
    }
  }
  if (cs == 0) {
    float tot = blockRed256(pe, sm1);
    if (t == 0) part_p[(b << 4) + blockIdx.y] = tot;
  }
  for (int j = 0; j < 2; ++j) {
    const int c = cs * 2 + j;
    const int gb = ((b * NCOIL + c) << 16) + (row << 8);
    float2 v[16];
    #pragma unroll
    for (int h2 = 0; h2 < 16; ++h2) {
      float2 cw = unpack_bf(csmh[gb + idx + (h2 << 4)]);
      v[h2] = cmulf(cw, pv[h2]);
    }
    dif16<0>(v);
    if (j) __syncthreads();
    #pragma unroll
    for (int rr = 0; rr < 16; ++rr) {
      int k1 = REV4[rr];
      v[rr] = cmulf(v[rr], twf[idx * k1]);
      trans[(k1 << 8) + (row16 << 4) + (idx ^ k1)] = v[rr];
    }
    __syncthreads();
    #pragma unroll
    for (int h1 = 0; h1 < 16; ++h1)
      v[h1] = trans[(idx << 8) + (row16 << 4) + (h1 ^ idx)];
    dif16<0>(v);
    #pragma unroll
    for (int rr = 0; rr < 16; ++rr)
      coil[gb + idx + (REV4[rr] << 4)] = pack_bf(v[rr]);
  }
}

__global__ __launch_bounds__(256) void k_fft_cols_mask(
    unsigned* __restrict__ coil, const float* __restrict__ mask,
    const float2* __restrict__ twf, float* __restrict__ part_m)
{
  __shared__ float2 trans[4096];
  __shared__ float smR[4];
  const int t = threadIdx.x;
  const int bc = blockIdx.x, b = bc / NCOIL;
  const int w0 = blockIdx.y << 4;
  const int col = t & 15, idx = t >> 4;
  const int base = (bc << 16) + w0 + col;
  float2 v[16];
  #pragma unroll
  for (int h2 = 0; h2 < 16; ++h2)
    v[h2] = unpack_bf(coil[base + ((idx + (h2 << 4)) << 8)]);
  dif16<0>(v);
  #pragma unroll
  for (int r = 0; r < 16; ++r) {
    int k1 = REV4[r];
    v[r] = cmulf(v[r], twf[idx * k1]);
    trans[(idx << 8) + (k1 << 4) + col] = v[r];
  }
  __syncthreads();
  #pragma unroll
  for (int h1 = 0; h1 < 16; ++h1)
    v[h1] = trans[(h1 << 8) + (idx << 4) + col];
  __syncthreads();
  dif16<0>(v);
  float pm = 0.f;
  #pragma unroll
  for (int r = 0; r < 16; ++r) {
    float mv = mask[(b << 16) + ((idx + (REV4[r] << 4)) << 8) + w0 + col];
    v[r].x *= mv; v[r].y *= mv;
    pm = fmaf(v[r].x, v[r].x, fmaf(v[r].y, v[r].y, pm));
  }
  float tot = blockRed256(pm, smR);
  if (t == 0) part_m[(bc << 4) + blockIdx.y] = tot;
  dit16<1>(v);
  #pragma unroll
  for (int r = 0; r < 16; ++r) {
    float2 w = twf[idx * r];
    v[r] = make_float2(v[r].x * w.x + v[r].y * w.y, v[r].y * w.x - v[r].x * w.y);
    trans[(idx << 8) + (r << 4) + col] = v[r];
  }
  __syncthreads();
  #pragma unroll
  for (int k1 = 0; k1 < 16; ++k1)
    v[k1] = trans[(k1 << 8) + (idx << 4) + col];
  dif16<1>(v);
  const float sc = 1.f / 256.f;
  #pragma unroll
  for (int r = 0; r < 16; ++r)
    coil[base + ((idx + (REV4[r] << 4)) << 8)] =
        pack_bf(make_float2(v[r].x * sc, v[r].y * sc));
}

__global__ __launch_bounds__(256) void k_ifft_rows_upd(
    const unsigned* __restrict__ coil, const unsigned* __restrict__ csmh,
    const float2* __restrict__ twf,
    const float2* __restrict__ p, float2* __restrict__ x, float2* __restrict__ r,
    const float* __restrict__ part_m, const float* __restrict__ part_p,
    const float* __restrict__ part_r_old, float* __restrict__ part_r_new,
    const float* __restrict__ lam, float* __restrict__ outp)
{
  __shared__ float2 trans[4096];
  __shared__ float2 sm2[4];
  __shared__ float smA[4];
  __shared__ float smB[4];
  const int t = threadIdx.x;
  const int b = blockIdx.x, rg = blockIdx.y;
  const int cgi = t >> 6, row4 = (t >> 4) & 3, idx = t & 15;
  const int row = (rg << 2) + row4;

  float se = 0.f, sp = 0.f, sr = 0.f;
  for (int i = t; i < 1536; i += 256) se += part_m[i];
  if (t < 128) sp = part_p[t];
  for (int i = t; i < 512; i += 256) sr += part_r_old[i];
  blockRed2(se, sp, sm2);
  sr = blockRed256(sr, smA);
  const float l = *lam;
  const float denom = se * (1.f / 65536.f) + l * sp;
  const float alpha = (sr > 1e-10f) ? sr / denom : 0.f;

  float2 acc[16];
  #pragma unroll
  for (int rr = 0; rr < 16; ++rr) acc[rr] = make_float2(0.f, 0.f);
  const int tb = cgi << 10;
  for (int j = 0; j < 3; ++j) {
    const int c = cgi * 3 + j;
    const int gb = ((b * NCOIL + c) << 16) + (row << 8);
    float2 v[16];
    #pragma unroll
    for (int rr = 0; rr < 16; ++rr)
      v[rr] = unpack_bf(coil[gb + idx + (REV4[rr] << 4)]);
    dit16<1>(v);
    if (j) __syncthreads();
    #pragma unroll
    for (int rr = 0; rr < 16; ++rr) {
      float2 w = twf[idx * rr];
      float2 z = v[rr];
      trans[tb + (rr << 6) + (row4 << 4) + (idx ^ rr)] =
          make_float2(z.x * w.x + z.y * w.y, z.y * w.x - z.x * w.y);
    }
    __syncthreads();
    #pragma unroll
    for (int k1 = 0; k1 < 16; ++k1)
      v[k1] = trans[tb + (idx << 6) + (row4 << 4) + (k1 ^ idx)];
    dif16<1>(v);
    #pragma unroll
    for (int rr = 0; rr < 16; ++rr) {
      int gi = gb + idx + (REV4[rr] << 4);
      float2 cw = unpack_bf(csmh[gi]);
      float2 z = v[rr];
      acc[rr].x += cw.x * z.x + cw.y * z.y;
      acc[rr].y += cw.x * z.y - cw.y * z.x;
    }
  }
  __syncthreads();
  #pragma unroll
  for (int rr = 0; rr < 16; ++rr) {
    int c = idx + (REV4[rr] << 4);
    trans[tb + (row4 << 8) + c] = acc[rr];
  }
  __syncthreads();
  const float inv2 = 1.f / 256.f;
  float s = 0.f;
  #pragma unroll
  for (int e = 0; e < 4; ++e) {
    int px = t + (e << 8);
    float2 s0 = trans[px];
    float2 s1 = trans[1024 + px];
    float2 s2 = trans[2048 + px];
    float2 s3 = trans[3072 + px];
    float sx = (s0.x + s1.x) + (s2.x + s3.x);
    float sy = (s0.y + s1.y) + (s2.y + s3.y);
    int off = (rg << 10) + px;
    int gi = (b << 16) + off;
    float2 pvv = p[gi], xv = x[gi], rv = r[gi];
    float2 apv = make_float2(fmaf(l, pvv.x, sx * inv2), fmaf(l, pvv.y, sy * inv2));
    xv.x = fmaf(alpha, pvv.x, xv.x); xv.y = fmaf(alpha, pvv.y, xv.y);
    rv.x = fmaf(-alpha, apv.x, rv.x); rv.y = fmaf(-alpha, apv.y, rv.y);
    x[gi] = xv; r[gi] = rv;
    if (outp) {
      outp[(b << 17) + off] = xv.x;
      outp[(b << 17) + 65536 + off] = xv.y;
    }
    s = fmaf(rv.x, rv.x, fmaf(rv.y, rv.y, s));
  }
  float tot = blockRed256(s, smB);
  if (t == 0) part_r_new[(b << 6) + rg] = tot;
}

__global__ __launch_bounds__(256) void k_cg_init(
    const float2* __restrict__ rhs, float2* __restrict__ x,
    float2* __restrict__ r, float2* __restrict__ p, float* __restrict__ part)
{
  __shared__ float sm[4];
  const int t = threadIdx.x;
  const int base = blockIdx.x * 1024;
  float s = 0.f;
  #pragma unroll
  for (int e = 0; e < 4; ++e) {
    int idx = base + t + (e << 8);
    float2 v = rhs[idx];
    x[idx] = make_float2(0.f, 0.f);
    r[idx] = v; p[idx] = v;
    s = fmaf(v.x, v.x, fmaf(v.y, v.y, s));
  }
  float tot = blockRed256(s, sm);
  if (t == 0) part[blockIdx.x] = tot;
}

// ================= cooperative CG (512 blocks, min 2 waves/EU) =================
__global__ __launch_bounds__(256, 2) void k_cg_coop(
    const float2* __restrict__ rhs,
    float2* __restrict__ x, float2* __restrict__ r,
    float2* __restrict__ pbuf0, float2* __restrict__ pbuf1,
    const unsigned* __restrict__ csmh, const float2* __restrict__ twf,
    unsigned* __restrict__ coil, const float* __restrict__ mask,
    float* __restrict__ part_r, float* __restrict__ part_m,
    float* __restrict__ part_p, const float* __restrict__ lam,
    float* __restrict__ outp)
{
  __shared__ float2 trans[4096];
  __shared__ float2 sm2[4];
  __shared__ float smA[4];
  __shared__ float smB[4];
  cgx::grid_group grid = cgx::this_grid();
  const int bid = blockIdx.x;
  const int t = threadIdx.x;

  // ---- phase 0: init ----
  {
    const int base = bid * 1024;
    float s = 0.f;
    #pragma unroll
    for (int e = 0; e < 4; ++e) {
      int idx = base + t + (e << 8);
      float2 v = rhs[idx];
      x[idx] = make_float2(0.f, 0.f);
      r[idx] = v; pbuf0[idx] = v;
      s = fmaf(v.x, v.x, fmaf(v.y, v.y, s));
    }
    float tot = blockRed256(s, smA);
    if (t == 0) part_r[bid] = tot;
  }
  grid.sync();

  for (int it = 0; it < 11; ++it) {
    float2* p_cur = (it % 2 == 0) ? pbuf0 : pbuf1;
    float2* p_prv = (it == 0) ? pbuf0 : ((it % 2 == 0) ? pbuf1 : pbuf0);
    const float* pro = part_r + (it > 0 ? (it - 1) : 0) * 512;
    const float* prn = part_r + it * 512;
    float* prnew = part_r + (it + 1) * 512;
    const bool first = (it == 0);

    // ---- phase 1 ----
    {
      const int b = bid >> 6, rem = bid & 63;
      const int rg = rem >> 2, cs = rem & 3;
      const int idx = t & 15, row16 = t >> 4;
      const int row = (rg << 4) + row16;

      float beta = 0.f; bool do_upd = false;
      if (!first) {
        float so = 0.f, sn = 0.f;
        for (int i = t; i < 512; i += 256) { so += pro[i]; sn += prn[i]; }
        blockRed2(so, sn, sm2);
        do_upd = so > 1e-10f;
        beta = do_upd ? sn / so : 0.f;
      }
      const int pb = (b << 16) + (row << 8);
      float2 pv[16];
      float pe = 0.f;
      #pragma unroll
      for (int h2 = 0; h2 < 16; ++h2) {
        int n = idx + (h2 << 4);
        float2 t0 = p_prv[pb + n];
        if (!first && do_upd) {
          float2 rv = r[pb + n];
          t0 = make_float2(fmaf(beta, t0.x, rv.x), fmaf(beta, t0.y, rv.y));
        }
        pv[h2] = t0;
        if (cs == 0) {
          if (!first) p_cur[pb + n] = t0;
          pe = fmaf(t0.x, t0.x, fmaf(t0.y, t0.y, pe));
        }
      }
      if (cs == 0) {
        float tot = blockRed256(pe, smA);
        if (t == 0) part_p[(b << 4) + rg] = tot;
      }
      for (int j = 0; j < 3; ++j) {
        const int c = cs * 3 + j;
        const int gb = ((b * NCOIL + c) << 16) + (row << 8);
        float2 v[16];
        #pragma unroll
        for (int h2 = 0; h2 < 16; ++h2) {
          float2 cw = unpack_bf(csmh[gb + idx + (h2 << 4)]);
          v[h2] = cmulf(cw, pv[h2]);
        }
        dif16<0>(v);
        if (j) __syncthreads();
        #pragma unroll
        for (int rr = 0; rr < 16; ++rr) {
          int k1 = REV4[rr];
          v[rr] = cmulf(v[rr], twf[idx * k1]);
          trans[(k1 << 8) + (row16 << 4) + (idx ^ k1)] = v[rr];
        }
        __syncthreads();
        #pragma unroll
        for (int h1 = 0; h1 < 16; ++h1)
          v[h1] = trans[(idx << 8) + (row16 << 4) + (h1 ^ idx)];
        dif16<0>(v);
        #pragma unroll
        for (int rr = 0; rr < 16; ++rr)
          coil[gb + idx + (REV4[rr] << 4)] = pack_bf(v[rr]);
      }
    }
    grid.sync();

    // ---- phase 2 (3 units/block) ----
    for (int k = 0; k < 3; ++k) {
      const int u = bid * 3 + k;
      const int bc = u >> 4, b = bc / NCOIL;
      const int w0 = (u & 15) << 4;
      const int col = t & 15, idx = t >> 4;
      const int base = (bc << 16) + w0 + col;
      if (k) __syncthreads();
      float2 v[16];
      #pragma unroll
      for (int h2 = 0; h2 < 16; ++h2)
        v[h2] = unpack_bf(coil[base + ((idx + (h2 << 4)) << 8)]);
      dif16<0>(v);
      #pragma unroll
      for (int rr = 0; rr < 16; ++rr) {
        int k1 = REV4[rr];
        v[rr] = cmulf(v[rr], twf[idx * k1]);
        trans[(idx << 8) + (k1 << 4) + col] = v[rr];
      }
      __syncthreads();
      #pragma unroll
      for (int h1 = 0; h1 < 16; ++h1)
        v[h1] = trans[(h1 << 8) + (idx << 4) + col];
      __syncthreads();
      dif16<0>(v);
      float pm = 0.f;
      #pragma unroll
      for (int rr = 0; rr < 16; ++rr) {
        float mv = mask[(b << 16) + ((idx + (REV4[rr] << 4)) << 8) + w0 + col];
        v[rr].x *= mv; v[rr].y *= mv;
        pm = fmaf(v[rr].x, v[rr].x, fmaf(v[rr].y, v[rr].y, pm));
      }
      float tot = blockRed256(pm, smA);
      if (t == 0) part_m[u] = tot;
      dit16<1>(v);
      #pragma unroll
      for (int rr = 0; rr < 16; ++rr) {
        float2 w = twf[idx * rr];
        v[rr] = make_float2(v[rr].x * w.x + v[rr].y * w.y, v[rr].y * w.x - v[rr].x * w.y);
        trans[(idx << 8) + (rr << 4) + col] = v[rr];
      }
      __syncthreads();
      #pragma unroll
      for (int k1 = 0; k1 < 16; ++k1)
        v[k1] = trans[(k1 << 8) + (idx << 4) + col];
      dif16<1>(v);
      const float sc = 1.f / 256.f;
      #pragma unroll
      for (int rr = 0; rr < 16; ++rr)
        coil[base + ((idx + (REV4[rr] << 4)) << 8)] =
            pack_bf(make_float2(v[rr].x * sc, v[rr].y * sc));
    }
    grid.sync();

    // ---- phase 3 ----
    {
      const int b = bid >> 6, rg = bid & 63;
      const int cgi = t >> 6, row4 = (t >> 4) & 3, idx = t & 15;
      const int row = (rg << 2) + row4;

      float se = 0.f, sp = 0.f, sr = 0.f;
      for (int i = t; i < 1536; i += 256) se += part_m[i];
      if (t < 128) sp = part_p[t];
      for (int i = t; i < 512; i += 256) sr += prn[i];
      blockRed2(se, sp, sm2);
      sr = blockRed256(sr, smA);
      const float l = *lam;
      const float denom = se * (1.f / 65536.f) + l * sp;
      const float alpha = (sr > 1e-10f) ? sr / denom : 0.f;

      float2 acc[16];
      #pragma unroll
      for (int rr = 0; rr < 16; ++rr) acc[rr] = make_float2(0.f, 0.f);
      const int tb = cgi << 10;
      for (int j = 0; j < 3; ++j) {
        const int c = cgi * 3 + j;
        const int gb = ((b * NCOIL + c) << 16) + (row << 8);
        float2 v[16];
        #pragma unroll
        for (int rr = 0; rr < 16; ++rr)
          v[rr] = unpack_bf(coil[gb + idx + (REV4[rr] << 4)]);
        dit16<1>(v);
        if (j) __syncthreads();
        #pragma unroll
        for (int rr = 0; rr < 16; ++rr) {
          float2 w = twf[idx * rr];
          float2 z = v[rr];
          trans[tb + (rr << 6) + (row4 << 4) + (idx ^ rr)] =
              make_float2(z.x * w.x + z.y * w.y, z.y * w.x - z.x * w.y);
        }
        __syncthreads();
        #pragma unroll
        for (int k1 = 0; k1 < 16; ++k1)
          v[k1] = trans[tb + (idx << 6) + (row4 << 4) + (k1 ^ idx)];
        dif16<1>(v);
        #pragma unroll
        for (int rr = 0; rr < 16; ++rr) {
          int gi = gb + idx + (REV4[rr] << 4);
          float2 cw = unpack_bf(csmh[gi]);
          float2 z = v[rr];
          acc[rr].x += cw.x * z.x + cw.y * z.y;
          acc[rr].y += cw.x * z.y - cw.y * z.x;
        }
      }
      __syncthreads();
      #pragma unroll
      for (int rr = 0; rr < 16; ++rr) {
        int c = idx + (REV4[rr] << 4);
        trans[tb + (row4 << 8) + c] = acc[rr];
      }
      __syncthreads();
      const float inv2 = 1.f / 256.f;
      float s = 0.f;
      #pragma unroll
      for (int e = 0; e < 4; ++e) {
        int px = t + (e << 8);
        float2 s0 = trans[px];
        float2 s1 = trans[1024 + px];
        float2 s2 = trans[2048 + px];
        float2 s3 = trans[3072 + px];
        float sx = (s0.x + s1.x) + (s2.x + s3.x);
        float sy = (s0.y + s1.y) + (s2.y + s3.y);
        int off = (rg << 10) + px;
        int gi = (b << 16) + off;
        float2 pvv = p_cur[gi], xv = x[gi], rv = r[gi];
        float2 apv = make_float2(fmaf(l, pvv.x, sx * inv2), fmaf(l, pvv.y, sy * inv2));
        xv.x = fmaf(alpha, pvv.x, xv.x); xv.y = fmaf(alpha, pvv.y, xv.y);
        rv.x = fmaf(-alpha, apv.x, rv.x); rv.y = fmaf(-alpha, apv.y, rv.y);
        x[gi] = xv; r[gi] = rv;
        if (it == 10) {
          outp[(b << 17) + off] = xv.x;
          outp[(b << 17) + 65536 + off] = xv.y;
        }
        s = fmaf(rv.x, rv.x, fmaf(rv.y, rv.y, s));
      }
      float tot = blockRed256(s, smB);
      if (t == 0) prnew[(b << 6) + rg] = tot;
    }
    if (it < 10) grid.sync();
  }
}

// ---------------- driver ----------------
extern "C" void kernel_launch(void* const* d_in, const int* in_sizes, int n_in,
                              void* d_out, int out_size, void* d_ws, size_t ws_size,
                              hipStream_t stream) {
  (void)in_sizes; (void)n_in; (void)out_size; (void)ws_size;
  const float* atb   = (const float*)d_in[0];
  const float* csm_r = (const float*)d_in[1];
  const float* csm_i = (const float*)d_in[2];
  const float* mask  = (const float*)d_in[3];
  const float* w1 = (const float*)d_in[4];  const float* b1 = (const float*)d_in[5];
  const float* w2 = (const float*)d_in[6];  const float* b2 = (const float*)d_in[7];
  const float* w3 = (const float*)d_in[8];  const float* b3 = (const float*)d_in[9];
  const float* w4 = (const float*)d_in[10]; const float* b4 = (const float*)d_in[11];
  const float* w5 = (const float*)d_in[12]; const float* b5 = (const float*)d_in[13];
  const float* lam = (const float*)d_in[14];

  char* ws = (char*)d_ws;   // ws_size = 256 MiB
  unsigned short* actA = (unsigned short*)ws;                  // 64 MiB
  unsigned short* actB = (unsigned short*)(ws + 67108864);     // 64 MiB
  unsigned* coil   = (unsigned*)(ws + 134217728);              // 25165824 B (bf16x2)
  float2* x        = (float2*)(ws + 176160768);                // 4 MiB
  float2* r        = (float2*)(ws + 180355072);
  float2* pbuf0    = (float2*)(ws + 184549376);
  float2* rhs      = (float2*)(ws + 188743680);                // doubles as pbuf1
  float2* pbuf1    = rhs;
  unsigned* csmh   = (unsigned*)(ws + 192937984);              // 25165824 B
  float*  w1T      = (float*)(ws + 218103808);                 // 4608 B
  unsigned short* bf2 = (unsigned short*)(ws + 218108416);     // 73728 B each
  unsigned short* bf3 = (unsigned short*)(ws + 218182144);
  unsigned short* bf4 = (unsigned short*)(ws + 218255872);
  unsigned short* bf5 = (unsigned short*)(ws + 218329600);     // 18432 B
  float2* twf      = (float2*)(ws + 218348032);                // 2048 B
  float*  part_r   = (float*)(ws + 218350080);                 // 12*512*4 = 24576 B
  float*  part_m   = (float*)(ws + 218374656);                 // 1536*4
  float*  part_p   = (float*)(ws + 218380800);                 // 128*4

  // prep
  k_prep<<<25050, 256, 0, stream>>>(w1, w2, w3, w4, w5, csm_r, csm_i,
                                    w1T, bf2, bf3, bf4, bf5, csmh, twf);

  // CNN
  k_conv1<<<dim3(16, 16, 8), 256, 0, stream>>>(atb, w1T, b1, actA);
  k_conv_mfma<<<dim3(16, 16, 8), 256, 0, stream>>>(actA, bf2, b2, actB);
  k_conv_mfma<<<dim3(16, 16, 8), 256, 0, stream>>>(actB, bf3, b3, actA);
  k_conv_mfma<<<dim3(16, 16, 8), 256, 0, stream>>>(actA, bf4, b4, actB);
  k_conv5_rhs<<<dim3(16, 16, 8), 512, 0, stream>>>(actB, bf5, b5, atb, lam, rhs);

  // CG: try the cooperative mega-kernel; fall back to the proven 3-kernel loop.
  float* outp = (float*)d_out;
  void* args[] = {
    (void*)&rhs, (void*)&x, (void*)&r, (void*)&pbuf0, (void*)&pbuf1,
    (void*)&csmh, (void*)&twf, (void*)&coil, (void*)&mask,
    (void*)&part_r, (void*)&part_m, (void*)&part_p, (void*)&lam, (void*)&outp
  };
  hipError_t ce = hipLaunchCooperativeKernel((void*)k_cg_coop, dim3(512), dim3(256),
                                             args, 0, stream);
  if (ce != hipSuccess) {
    (void)hipGetLastError();   // clear sticky error
    k_cg_init<<<512, 256, 0, stream>>>(rhs, x, r, pbuf0, part_r);
    for (int it = 0; it < 11; ++it) {
      float2* p_cur = (it % 2 == 0) ? pbuf0 : pbuf1;
      float2* p_prv = (it == 0) ? pbuf0 : ((it % 2 == 0) ? pbuf1 : pbuf0);
      const float* pro = part_r + (it > 0 ? (it - 1) : 0) * 512;
      const float* prn = part_r + it * 512;
      k_coil_fft_rows<<<dim3(8, 16, 6), 256, 0, stream>>>(
          p_prv, r, p_cur, pro, prn, it == 0 ? 1 : 0, csmh, twf, coil, part_p);
      k_fft_cols_mask<<<dim3(96, 16), 256, 0, stream>>>(coil, mask, twf, part_m);
      k_ifft_rows_upd<<<dim3(8, 64), 256, 0, stream>>>(
          coil, csmh, twf, p_cur, x, r, part_m, part_p,
          part_r + it * 512, part_r + (it + 1) * 512, lam,
          it == 10 ? (float*)d_out : (float*)nullptr);
    }
  }
}

// Round 16
// 838.907 us; speedup vs baseline: 4.1057x; 4.1057x over previous
//
#include <hip/hip_runtime.h>
#include <hip/hip_bf16.h>
#include <math.h>

static constexpr int NCOIL = 12;
static constexpr int HWSZ  = 65536;   // 256*256

typedef short v8s __attribute__((ext_vector_type(8)));
typedef float v4f __attribute__((ext_vector_type(4)));

__device__ __forceinline__ unsigned short f2bf(float v) {
  __hip_bfloat16 h = __float2bfloat16(v);
  union { __hip_bfloat16 h; unsigned short u; } cv; cv.h = h; return cv.u;
}
__device__ __forceinline__ float bf2f(unsigned short u) {
  return __uint_as_float(((unsigned)u) << 16);
}
__device__ __forceinline__ unsigned pack_bf(float2 v) {
  return ((unsigned)f2bf(v.y) << 16) | (unsigned)f2bf(v.x);
}
__device__ __forceinline__ float2 unpack_bf(unsigned u) {
  return make_float2(bf2f((unsigned short)(u & 0xffffu)),
                     bf2f((unsigned short)(u >> 16)));
}

// ---------------- complex helpers ----------------
__device__ __forceinline__ float2 cmulf(float2 a, float2 b) {
  return make_float2(a.x * b.x - a.y * b.y, a.x * b.y + a.y * b.x);
}
__device__ __forceinline__ float2 caddf(float2 a, float2 b) {
  return make_float2(a.x + b.x, a.y + b.y);
}
__device__ __forceinline__ float2 csubf(float2 a, float2 b) {
  return make_float2(a.x - b.x, a.y - b.y);
}

// ---------------- block reductions ----------------
__device__ __forceinline__ float blockRed256(float v, float* sm) {
  #pragma unroll
  for (int off = 32; off; off >>= 1) v += __shfl_down(v, off);
  int lane = threadIdx.x & 63, wv = threadIdx.x >> 6;
  if (lane == 0) sm[wv] = v;
  __syncthreads();
  return sm[0] + sm[1] + sm[2] + sm[3];
}

__device__ __forceinline__ void blockRed2(float& a, float& b, float2* sm) {
  #pragma unroll
  for (int off = 32; off; off >>= 1) {
    a += __shfl_down(a, off);
    b += __shfl_down(b, off);
  }
  int lane = threadIdx.x & 63, wv = threadIdx.x >> 6;
  if (lane == 0) sm[wv] = make_float2(a, b);
  __syncthreads();
  float2 s0 = sm[0], s1 = sm[1], s2 = sm[2], s3 = sm[3];
  a = s0.x + s1.x + s2.x + s3.x;
  b = s0.y + s1.y + s2.y + s3.y;
}

// ---------------- in-register 16-pt DFT ----------------
__device__ __constant__ const float TC16[8] = {
  1.f, 0.92387953f, 0.70710678f, 0.38268343f, 0.f, -0.38268343f, -0.70710678f, -0.92387953f};
__device__ __constant__ const float TS16[8] = {
  0.f, -0.38268343f, -0.70710678f, -0.92387953f, -1.f, -0.92387953f, -0.70710678f, -0.38268343f};
__device__ __constant__ const int REV4[16] = {0,8,4,12,2,10,6,14,1,9,5,13,3,11,7,15};

template<int INV>
__device__ __forceinline__ void dif16(float2 v[16]) {
  #pragma unroll
  for (int ls = 0; ls < 4; ++ls) {
    const int len = 16 >> ls, half = len >> 1, step = 1 << ls;
    #pragma unroll
    for (int i = 0; i < 16; i += len) {
      #pragma unroll
      for (int j = 0; j < half; ++j) {
        float2 a = v[i + j], b = v[i + j + half];
        v[i + j] = caddf(a, b);
        float2 d = csubf(a, b);
        float cr = TC16[j * step];
        float ci = INV ? -TS16[j * step] : TS16[j * step];
        v[i + j + half] = make_float2(d.x * cr - d.y * ci, d.x * ci + d.y * cr);
      }
    }
  }
}

template<int INV>
__device__ __forceinline__ void dit16(float2 v[16]) {
  #pragma unroll
  for (int ls = 0; ls < 4; ++ls) {
    const int len = 2 << ls, half = len >> 1, step = 16 / len;
    #pragma unroll
    for (int i = 0; i < 16; i += len) {
      #pragma unroll
      for (int j = 0; j < half; ++j) {
        float cr = TC16[j * step];
        float ci = INV ? -TS16[j * step] : TS16[j * step];
        float2 b = v[i + j + half];
        float2 tt = make_float2(b.x * cr - b.y * ci, b.x * ci + b.y * cr);
        float2 a = v[i + j];
        v[i + j] = caddf(a, tt);
        v[i + j + half] = csubf(a, tt);
      }
    }
  }
}

// ---------------- merged prep kernel ----------------
__global__ __launch_bounds__(256) void k_prep(
    const float* __restrict__ w1, const float* __restrict__ w2,
    const float* __restrict__ w3, const float* __restrict__ w4,
    const float* __restrict__ w5, const float* __restrict__ csm_r,
    const float* __restrict__ csm_i,
    float* __restrict__ w1T, unsigned short* __restrict__ bf2,
    unsigned short* __restrict__ bf3, unsigned short* __restrict__ bf4,
    unsigned short* __restrict__ bf5, unsigned* __restrict__ csmh,
    float2* __restrict__ twf)
{
  const int bx = blockIdx.x;
  const int t = threadIdx.x;
  if (bx < 24576) {
    int i = bx * 256 + t;
    csmh[i] = ((unsigned)f2bf(csm_i[i]) << 16) | (unsigned)f2bf(csm_r[i]);
    return;
  }
  int r = bx - 24576;
  if (r < 432) {
    const float* w = (r < 144) ? w2 : (r < 288) ? w3 : w4;
    unsigned short* bf = (r < 144) ? bf2 : (r < 288) ? bf3 : bf4;
    int i = (r % 144) * 256 + t;
    int j = i & 7, lane = (i >> 3) & 63, ocg = (i >> 9) & 3, ks = i >> 11;
    int oc = (ocg << 4) + (lane & 15);
    int ic = ((ks & 1) << 5) + (((lane >> 4) & 3) << 3) + j;
    bf[i] = f2bf(w[(oc * 64 + ic) * 9 + (ks >> 1)]);
    return;
  }
  r -= 432;
  if (r < 36) {
    int i = r * 256 + t;
    int j = i & 7, lane = (i >> 3) & 63, ks = i >> 9;
    int oc = lane & 15;
    int ic = ((ks & 1) << 5) + (((lane >> 4) & 3) << 3) + j;
    bf5[i] = (oc < 2) ? f2bf(w5[(oc * 64 + ic) * 9 + (ks >> 1)]) : (unsigned short)0;
    return;
  }
  r -= 36;
  if (r < 5) {
    int i = r * 256 + t;
    if (i < 1152) {
      int oc = i & 63;
      int rest = i >> 6;            // ic*9+k
      int ic = rest / 9, k = rest - ic * 9;
      w1T[i] = w1[(oc * 2 + ic) * 9 + k];
    }
    return;
  }
  float ang = -6.28318530717958647692f * (float)t / 256.f;
  float s, c; sincosf(ang, &s, &c);
  twf[t] = make_float2(c, s);
}

// ---------------- layer 1: fp32 direct conv (IC=2), out pixel-major bf16 ----------------
__global__ __launch_bounds__(256) void k_conv1(
    const float* __restrict__ atb,
    const float* __restrict__ w1T,
    const float* __restrict__ b1,
    unsigned short* __restrict__ out)
{
  __shared__ float patch[2 * 324];
  const int t = threadIdx.x;
  const int img = blockIdx.z;
  const float* in = atb + (size_t)img * 131072;
  const int tx0 = blockIdx.x << 4, ty0 = blockIdx.y << 4;
  for (int i = t; i < 648; i += 256) {
    int ic = i / 324, rem = i - ic * 324;
    int py = rem / 18, px = rem - py * 18;
    int gy = ty0 + py - 1, gx = tx0 + px - 1;
    float v = 0.f;
    if ((unsigned)gy < 256u && (unsigned)gx < 256u)
      v = in[(ic << 16) + (gy << 8) + gx];
    patch[i] = v;
  }
  __syncthreads();
  const int tx = t & 15, ty = t >> 4;
  float acc[64];
  #pragma unroll
  for (int o = 0; o < 64; ++o) acc[o] = 0.f;
  #pragma unroll
  for (int ic = 0; ic < 2; ++ic) {
    const float* pb = &patch[ic * 324 + ty * 18 + tx];
    #pragma unroll
    for (int k = 0; k < 9; ++k) {
      const float v = pb[(k / 3) * 18 + (k % 3)];
      const float* wr = &w1T[(ic * 9 + k) << 6];
      #pragma unroll
      for (int o = 0; o < 64; ++o) acc[o] = fmaf(v, wr[o], acc[o]);
    }
  }
  size_t obase = ((size_t)img << 22) + ((size_t)(((ty0 + ty) << 8) + tx0 + tx) << 6);
  v8s* outv = (v8s*)(out + obase);
  #pragma unroll
  for (int g = 0; g < 8; ++g) {
    v8s ov;
    #pragma unroll
    for (int j = 0; j < 8; ++j) {
      float v = fmaxf(acc[(g << 3) + j] + b1[(g << 3) + j], 0.f);
      ov[j] = (short)f2bf(v);
    }
    outv[g] = ov;
  }
}

// ---- layers 2-4: bf16 MFMA implicit GEMM, 16x16 tile, 4 waves x (4 rows x 64 oc) ----
__global__ __launch_bounds__(256, 3) void k_conv_mfma(
    const unsigned short* __restrict__ in,
    const unsigned short* __restrict__ bfrag,
    const float* __restrict__ bias,
    unsigned short* __restrict__ out)
{
  __shared__ v8s halo[2592];   // 41472 B
  __shared__ v8s bsh[768];     // 12288 B
  char* hb = (char*)halo;
  const int t = threadIdx.x;
  const int img = blockIdx.z;
  const int tx0 = blockIdx.x << 4, ty0 = blockIdx.y << 4;
  const size_t ibase = ((size_t)img << 22);
  for (int c = t; c < 2592; c += 256) {
    int hy = c / 144, rem = c - hy * 144;
    int hx = rem >> 3, slot = rem & 7;
    int gy = ty0 + hy - 1, gx = tx0 + hx - 1;
    v8s v = {0, 0, 0, 0, 0, 0, 0, 0};
    if ((unsigned)gy < 256u && (unsigned)gx < 256u)
      v = *(const v8s*)(in + ibase + ((size_t)((gy << 8) + gx) << 6) + (slot << 3));
    int xl = hy * 18 + hx;
    *(v8s*)(hb + xl * 128 + ((slot ^ (xl & 7)) << 4)) = v;
  }
  const v8s* bg = (const v8s*)bfrag;
  v8s breg[3];
  #pragma unroll
  for (int i = 0; i < 3; ++i) breg[i] = bg[t + (i << 8)];
  #pragma unroll
  for (int i = 0; i < 3; ++i) bsh[t + (i << 8)] = breg[i];
  #pragma unroll
  for (int i = 0; i < 3; ++i) breg[i] = bg[768 + t + (i << 8)];
  __syncthreads();

  const int lane = t & 63, w = t >> 6;
  const int px = lane & 15, lg = lane >> 4;
  v4f acc[4][4];
  #pragma unroll
  for (int pf = 0; pf < 4; ++pf)
    #pragma unroll
    for (int og = 0; og < 4; ++og)
      #pragma unroll
      for (int rg = 0; rg < 4; ++rg) acc[pf][og][rg] = 0.f;

  #pragma unroll
  for (int chunk = 0; chunk < 6; ++chunk) {
    #pragma unroll
    for (int k3 = 0; k3 < 3; ++k3) {
      const int ks = chunk * 3 + k3;
      const int tap = ks >> 1;
      const int dy = tap / 3, dx = tap - dy * 3;
      const int slot = ((ks & 1) << 2) | lg;
      v8s b0 = bsh[((k3 << 2) | 0) * 64 + lane];
      v8s b1 = bsh[((k3 << 2) | 1) * 64 + lane];
      v8s b2 = bsh[((k3 << 2) | 2) * 64 + lane];
      v8s b3 = bsh[((k3 << 2) | 3) * 64 + lane];
      #pragma unroll
      for (int pf = 0; pf < 4; ++pf) {
        int xl = (w * 4 + pf + dy) * 18 + px + dx;
        v8s a = *(const v8s*)(hb + xl * 128 + ((slot ^ (xl & 7)) << 4));
        acc[pf][0] = __builtin_amdgcn_mfma_f32_16x16x32_bf16(a, b0, acc[pf][0], 0, 0, 0);
        acc[pf][1] = __builtin_amdgcn_mfma_f32_16x16x32_bf16(a, b1, acc[pf][1], 0, 0, 0);
        acc[pf][2] = __builtin_amdgcn_mfma_f32_16x16x32_bf16(a, b2, acc[pf][2], 0, 0, 0);
        acc[pf][3] = __builtin_amdgcn_mfma_f32_16x16x32_bf16(a, b3, acc[pf][3], 0, 0, 0);
      }
    }
    if (chunk < 5) {
      __syncthreads();
      #pragma unroll
      for (int i = 0; i < 3; ++i) bsh[t + (i << 8)] = breg[i];
      if (chunk < 4) {
        #pragma unroll
        for (int i = 0; i < 3; ++i) breg[i] = bg[(chunk + 2) * 768 + t + (i << 8)];
      }
      __syncthreads();
    }
  }
  const int ocl = lane & 15;
  float bv[4];
  #pragma unroll
  for (int og = 0; og < 4; ++og) bv[og] = bias[(og << 4) + ocl];
  #pragma unroll
  for (int pf = 0; pf < 4; ++pf) {
    const int gy = ty0 + (w << 2) + pf;
    #pragma unroll
    for (int og = 0; og < 4; ++og) {
      const int oc = (og << 4) + ocl;
      #pragma unroll
      for (int rg = 0; rg < 4; ++rg) {
        float v = fmaxf(acc[pf][og][rg] + bv[og], 0.f);
        int gx = tx0 + (lg << 2) + rg;
        out[ibase + ((size_t)((gy << 8) + gx) << 6) + oc] = f2bf(v);
      }
    }
  }
}

// ---------------- layer 5 (64->2, MFMA) + rhs ----------------
__global__ __launch_bounds__(512, 4) void k_conv5_rhs(
    const unsigned short* __restrict__ in,
    const unsigned short* __restrict__ bf5,
    const float* __restrict__ b5,
    const float* __restrict__ atb,
    const float* __restrict__ lam,
    float2* __restrict__ rhs)
{
  __shared__ v8s halo[2592];
  char* hb = (char*)halo;
  const int t = threadIdx.x;
  const int img = blockIdx.z;
  const int tx0 = blockIdx.x << 4, ty0 = blockIdx.y << 4;
  const size_t ibase = ((size_t)img << 22);
  for (int c = t; c < 2592; c += 512) {
    int hy = c / 144, rem = c - hy * 144;
    int hx = rem >> 3, slot = rem & 7;
    int gy = ty0 + hy - 1, gx = tx0 + hx - 1;
    v8s v = {0, 0, 0, 0, 0, 0, 0, 0};
    if ((unsigned)gy < 256u && (unsigned)gx < 256u)
      v = *(const v8s*)(in + ibase + ((size_t)((gy << 8) + gx) << 6) + (slot << 3));
    int xl = hy * 18 + hx;
    *(v8s*)(hb + xl * 128 + ((slot ^ (xl & 7)) << 4)) = v;
  }
  __syncthreads();
  const int lane = t & 63, w = t >> 6;
  const int px = lane & 15, lg = lane >> 4;
  v4f acc[2];
  #pragma unroll
  for (int pf = 0; pf < 2; ++pf)
    #pragma unroll
    for (int rg = 0; rg < 4; ++rg) acc[pf][rg] = 0.f;
  #pragma unroll
  for (int ks = 0; ks < 18; ++ks) {
    const int tap = ks >> 1;
    const int dy = tap / 3, dx = tap - dy * 3;
    const int slot = ((ks & 1) << 2) | lg;
    v8s b = *(const v8s*)(bf5 + (((ks * 64) + lane) << 3));
    #pragma unroll
    for (int pf = 0; pf < 2; ++pf) {
      int xl = (w * 2 + pf + dy) * 18 + px + dx;
      v8s a = *(const v8s*)(hb + xl * 128 + ((slot ^ (xl & 7)) << 4));
      acc[pf] = __builtin_amdgcn_mfma_f32_16x16x32_bf16(a, b, acc[pf], 0, 0, 0);
    }
  }
  const int ocl = lane & 15;
  const float l = *lam;
  const float bsel = b5[ocl & 1];
  #pragma unroll
  for (int pf = 0; pf < 2; ++pf) {
    const int gy = ty0 + w * 2 + pf;
    #pragma unroll
    for (int rg = 0; rg < 4; ++rg) {
      float v = acc[pf][rg] + bsel;
      float d1 = __shfl_down(v, 1);
      if (ocl == 0) {
        int gx = tx0 + (lg << 2) + rg;
        int pix = (gy << 8) + gx;
        float x0 = atb[(size_t)img * 131072 + pix];
        float x1 = atb[(size_t)img * 131072 + 65536 + pix];
        rhs[(size_t)img * 65536 + pix] =
            make_float2(fmaf(l, x0 + v, x0), fmaf(l, x1 + d1, x1));
      }
    }
  }
}

// ---- AtA pass 1: (fused p-update) coil = csm*p (bf16 out), row FFT, part_p ----
// grid (8 b, 16 rowgroups, 4 cs): each block does 3 coils; p/r read 4x not 6x.
__global__ __launch_bounds__(256, 3) void k_coil_fft_rows(
    const float2* __restrict__ p_prev, const float2* __restrict__ r,
    float2* __restrict__ p_out,
    const float* __restrict__ part_r_old, const float* __restrict__ part_r_new,
    const int first,
    const unsigned* __restrict__ csmh, const float2* __restrict__ twf,
    unsigned* __restrict__ coil, float* __restrict__ part_p)
{
  __shared__ float2 trans[4096];
  __shared__ float2 sm2[4];
  __shared__ float sm1[4];
  const int t = threadIdx.x;
  const int b = blockIdx.x, cs = blockIdx.z;
  const int idx = t & 15, row16 = t >> 4;
  const int row = (blockIdx.y << 4) + row16;

  float beta = 0.f; bool do_upd = false;
  if (!first) {
    float so = 0.f, sn = 0.f;
    for (int i = t; i < 512; i += 256) { so += part_r_old[i]; sn += part_r_new[i]; }
    blockRed2(so, sn, sm2);
    do_upd = so > 1e-10f;
    beta = do_upd ? sn / so : 0.f;
  }
  const int pb = (b << 16) + (row << 8);
  float2 pv[16];
  float pe = 0.f;
  #pragma unroll
  for (int h2 = 0; h2 < 16; ++h2) {
    int n = idx + (h2 << 4);
    float2 t0 = p_prev[pb + n];
    if (!first && do_upd) {
      float2 rv = r[pb + n];
      t0 = make_float2(fmaf(beta, t0.x, rv.x), fmaf(beta, t0.y, rv.y));
    }
    pv[h2] = t0;
    if (cs == 0) {
      if (!first) p_out[pb + n] = t0;
      pe = fmaf(t0.x, t0.x, fmaf(t0.y, t0.y, pe));
    }
  }
  if (cs == 0) {
    float tot = blockRed256(pe, sm1);
    if (t == 0) part_p[(b << 4) + blockIdx.y] = tot;
  }
  for (int j = 0; j < 3; ++j) {
    const int c = cs * 3 + j;
    const int gb = ((b * NCOIL + c) << 16) + (row << 8);
    float2 v[16];
    #pragma unroll
    for (int h2 = 0; h2 < 16; ++h2) {
      float2 cw = unpack_bf(csmh[gb + idx + (h2 << 4)]);
      v[h2] = cmulf(cw, pv[h2]);
    }
    dif16<0>(v);
    if (j) __syncthreads();          // previous j's trans reads complete
    #pragma unroll
    for (int rr = 0; rr < 16; ++rr) {
      int k1 = REV4[rr];
      v[rr] = cmulf(v[rr], twf[idx * k1]);
      trans[(k1 << 8) + (row16 << 4) + (idx ^ k1)] = v[rr];
    }
    __syncthreads();
    #pragma unroll
    for (int h1 = 0; h1 < 16; ++h1)
      v[h1] = trans[(idx << 8) + (row16 << 4) + (h1 ^ idx)];
    dif16<0>(v);
    #pragma unroll
    for (int rr = 0; rr < 16; ++rr)
      coil[gb + idx + (REV4[rr] << 4)] = pack_bf(v[rr]);
  }
}

// ---- AtA pass 2: col FFT + mask (+part_m) + col IFFT, bf16 coil in/out ----
__global__ __launch_bounds__(256) void k_fft_cols_mask(
    unsigned* __restrict__ coil, const float* __restrict__ mask,
    const float2* __restrict__ twf, float* __restrict__ part_m)
{
  __shared__ float2 trans[4096];
  __shared__ float smR[4];
  const int t = threadIdx.x;
  const int bc = blockIdx.x, b = bc / NCOIL;
  const int w0 = blockIdx.y << 4;
  const int col = t & 15, idx = t >> 4;
  const int base = (bc << 16) + w0 + col;
  float2 v[16];
  #pragma unroll
  for (int h2 = 0; h2 < 16; ++h2)
    v[h2] = unpack_bf(coil[base + ((idx + (h2 << 4)) << 8)]);
  dif16<0>(v);
  #pragma unroll
  for (int r = 0; r < 16; ++r) {
    int k1 = REV4[r];
    v[r] = cmulf(v[r], twf[idx * k1]);
    trans[(idx << 8) + (k1 << 4) + col] = v[r];
  }
  __syncthreads();
  #pragma unroll
  for (int h1 = 0; h1 < 16; ++h1)
    v[h1] = trans[(h1 << 8) + (idx << 4) + col];
  __syncthreads();
  dif16<0>(v);
  float pm = 0.f;
  #pragma unroll
  for (int r = 0; r < 16; ++r) {
    float mv = mask[(b << 16) + ((idx + (REV4[r] << 4)) << 8) + w0 + col];
    v[r].x *= mv; v[r].y *= mv;
    pm = fmaf(v[r].x, v[r].x, fmaf(v[r].y, v[r].y, pm));
  }
  float tot = blockRed256(pm, smR);
  if (t == 0) part_m[(bc << 4) + blockIdx.y] = tot;
  dit16<1>(v);
  #pragma unroll
  for (int r = 0; r < 16; ++r) {
    float2 w = twf[idx * r];
    v[r] = make_float2(v[r].x * w.x + v[r].y * w.y, v[r].y * w.x - v[r].x * w.y);
    trans[(idx << 8) + (r << 4) + col] = v[r];
  }
  __syncthreads();
  #pragma unroll
  for (int k1 = 0; k1 < 16; ++k1)
    v[k1] = trans[(k1 << 8) + (idx << 4) + col];
  dif16<1>(v);
  const float sc = 1.f / 256.f;
  #pragma unroll
  for (int r = 0; r < 16; ++r)
    coil[base + ((idx + (REV4[r] << 4)) << 8)] =
        pack_bf(make_float2(v[r].x * sc, v[r].y * sc));
}

// ---- AtA pass 3 (fused update): row IFFT + conj(csm) sum + alpha + x/r update ----
__global__ __launch_bounds__(256) void k_ifft_rows_upd(
    const unsigned* __restrict__ coil, const unsigned* __restrict__ csmh,
    const float2* __restrict__ twf,
    const float2* __restrict__ p, float2* __restrict__ x, float2* __restrict__ r,
    const float* __restrict__ part_m, const float* __restrict__ part_p,
    const float* __restrict__ part_r_old, float* __restrict__ part_r_new,
    const float* __restrict__ lam, float* __restrict__ outp)
{
  __shared__ float2 trans[4096];
  __shared__ float2 sm2[4];
  __shared__ float smA[4];
  __shared__ float smB[4];
  const int t = threadIdx.x;
  const int b = blockIdx.x, rg = blockIdx.y;
  const int cgi = t >> 6, row4 = (t >> 4) & 3, idx = t & 15;
  const int row = (rg << 2) + row4;

  float se = 0.f, sp = 0.f, sr = 0.f;
  for (int i = t; i < 1536; i += 256) se += part_m[i];
  if (t < 128) sp = part_p[t];
  for (int i = t; i < 512; i += 256) sr += part_r_old[i];
  blockRed2(se, sp, sm2);
  sr = blockRed256(sr, smA);
  const float l = *lam;
  const float denom = se * (1.f / 65536.f) + l * sp;
  const float alpha = (sr > 1e-10f) ? sr / denom : 0.f;

  float2 acc[16];
  #pragma unroll
  for (int rr = 0; rr < 16; ++rr) acc[rr] = make_float2(0.f, 0.f);
  const int tb = cgi << 10;
  for (int j = 0; j < 3; ++j) {
    const int c = cgi * 3 + j;
    const int gb = ((b * NCOIL + c) << 16) + (row << 8);
    float2 v[16];
    #pragma unroll
    for (int rr = 0; rr < 16; ++rr)
      v[rr] = unpack_bf(coil[gb + idx + (REV4[rr] << 4)]);
    dit16<1>(v);
    if (j) __syncthreads();
    #pragma unroll
    for (int rr = 0; rr < 16; ++rr) {
      float2 w = twf[idx * rr];
      float2 z = v[rr];
      trans[tb + (rr << 6) + (row4 << 4) + (idx ^ rr)] =
          make_float2(z.x * w.x + z.y * w.y, z.y * w.x - z.x * w.y);
    }
    __syncthreads();
    #pragma unroll
    for (int k1 = 0; k1 < 16; ++k1)
      v[k1] = trans[tb + (idx << 6) + (row4 << 4) + (k1 ^ idx)];
    dif16<1>(v);
    #pragma unroll
    for (int rr = 0; rr < 16; ++rr) {
      int gi = gb + idx + (REV4[rr] << 4);
      float2 cw = unpack_bf(csmh[gi]);
      float2 z = v[rr];
      acc[rr].x += cw.x * z.x + cw.y * z.y;
      acc[rr].y += cw.x * z.y - cw.y * z.x;
    }
  }
  __syncthreads();
  #pragma unroll
  for (int rr = 0; rr < 16; ++rr) {
    int c = idx + (REV4[rr] << 4);
    trans[tb + (row4 << 8) + c] = acc[rr];
  }
  __syncthreads();
  const float inv2 = 1.f / 256.f;
  float s = 0.f;
  #pragma unroll
  for (int e = 0; e < 4; ++e) {
    int px = t + (e << 8);
    float2 s0 = trans[px];
    float2 s1 = trans[1024 + px];
    float2 s2 = trans[2048 + px];
    float2 s3 = trans[3072 + px];
    float sx = (s0.x + s1.x) + (s2.x + s3.x);
    float sy = (s0.y + s1.y) + (s2.y + s3.y);
    int off = (rg << 10) + px;
    int gi = (b << 16) + off;
    float2 pvv = p[gi], xv = x[gi], rv = r[gi];
    float2 apv = make_float2(fmaf(l, pvv.x, sx * inv2), fmaf(l, pvv.y, sy * inv2));
    xv.x = fmaf(alpha, pvv.x, xv.x); xv.y = fmaf(alpha, pvv.y, xv.y);
    rv.x = fmaf(-alpha, apv.x, rv.x); rv.y = fmaf(-alpha, apv.y, rv.y);
    x[gi] = xv; r[gi] = rv;
    if (outp) {
      outp[(b << 17) + off] = xv.x;
      outp[(b << 17) + 65536 + off] = xv.y;
    }
    s = fmaf(rv.x, rv.x, fmaf(rv.y, rv.y, s));
  }
  float tot = blockRed256(s, smB);
  if (t == 0) part_r_new[(b << 6) + rg] = tot;
}

// ---------------- CG init (512 blocks x 1024 elems) ----------------
__global__ __launch_bounds__(256) void k_cg_init(
    const float2* __restrict__ rhs, float2* __restrict__ x,
    float2* __restrict__ r, float2* __restrict__ p, float* __restrict__ part)
{
  __shared__ float sm[4];
  const int t = threadIdx.x;
  const int base = blockIdx.x * 1024;
  float s = 0.f;
  #pragma unroll
  for (int e = 0; e < 4; ++e) {
    int idx = base + t + (e << 8);
    float2 v = rhs[idx];
    x[idx] = make_float2(0.f, 0.f);
    r[idx] = v; p[idx] = v;
    s = fmaf(v.x, v.x, fmaf(v.y, v.y, s));
  }
  float tot = blockRed256(s, sm);
  if (t == 0) part[blockIdx.x] = tot;
}

// ---------------- driver ----------------
extern "C" void kernel_launch(void* const* d_in, const int* in_sizes, int n_in,
                              void* d_out, int out_size, void* d_ws, size_t ws_size,
                              hipStream_t stream) {
  (void)in_sizes; (void)n_in; (void)out_size; (void)ws_size;
  const float* atb   = (const float*)d_in[0];
  const float* csm_r = (const float*)d_in[1];
  const float* csm_i = (const float*)d_in[2];
  const float* mask  = (const float*)d_in[3];
  const float* w1 = (const float*)d_in[4];  const float* b1 = (const float*)d_in[5];
  const float* w2 = (const float*)d_in[6];  const float* b2 = (const float*)d_in[7];
  const float* w3 = (const float*)d_in[8];  const float* b3 = (const float*)d_in[9];
  const float* w4 = (const float*)d_in[10]; const float* b4 = (const float*)d_in[11];
  const float* w5 = (const float*)d_in[12]; const float* b5 = (const float*)d_in[13];
  const float* lam = (const float*)d_in[14];

  char* ws = (char*)d_ws;   // ws_size = 256 MiB
  unsigned short* actA = (unsigned short*)ws;                  // 64 MiB
  unsigned short* actB = (unsigned short*)(ws + 67108864);     // 64 MiB
  unsigned* coil   = (unsigned*)(ws + 134217728);              // 25165824 B (bf16x2)
  float2* x        = (float2*)(ws + 176160768);                // 4 MiB
  float2* r        = (float2*)(ws + 180355072);
  float2* pbuf0    = (float2*)(ws + 184549376);
  float2* rhs      = (float2*)(ws + 188743680);                // doubles as pbuf1
  float2* pbuf1    = rhs;
  unsigned* csmh   = (unsigned*)(ws + 192937984);              // 25165824 B
  float*  w1T      = (float*)(ws + 218103808);                 // 4608 B
  unsigned short* bf2 = (unsigned short*)(ws + 218108416);     // 73728 B each
  unsigned short* bf3 = (unsigned short*)(ws + 218182144);
  unsigned short* bf4 = (unsigned short*)(ws + 218255872);
  unsigned short* bf5 = (unsigned short*)(ws + 218329600);     // 18432 B
  float2* twf      = (float2*)(ws + 218348032);                // 2048 B
  float*  part_r   = (float*)(ws + 218350080);                 // 12*512*4 = 24576 B
  float*  part_m   = (float*)(ws + 218374656);                 // 1536*4
  float*  part_p   = (float*)(ws + 218380800);                 // 128*4

  // prep
  k_prep<<<25050, 256, 0, stream>>>(w1, w2, w3, w4, w5, csm_r, csm_i,
                                    w1T, bf2, bf3, bf4, bf5, csmh, twf);

  // CNN
  k_conv1<<<dim3(16, 16, 8), 256, 0, stream>>>(atb, w1T, b1, actA);
  k_conv_mfma<<<dim3(16, 16, 8), 256, 0, stream>>>(actA, bf2, b2, actB);
  k_conv_mfma<<<dim3(16, 16, 8), 256, 0, stream>>>(actB, bf3, b3, actA);
  k_conv_mfma<<<dim3(16, 16, 8), 256, 0, stream>>>(actA, bf4, b4, actB);
  k_conv5_rhs<<<dim3(16, 16, 8), 512, 0, stream>>>(actB, bf5, b5, atb, lam, rhs);

  // CG (split kernels; cooperative grid.sync measured at ~95 us/sync -> rejected)
  k_cg_init<<<512, 256, 0, stream>>>(rhs, x, r, pbuf0, part_r);
  for (int it = 0; it < 11; ++it) {
    float2* p_cur = (it % 2 == 0) ? pbuf0 : pbuf1;
    float2* p_prv = (it == 0) ? pbuf0 : ((it % 2 == 0) ? pbuf1 : pbuf0);
    const float* pro = part_r + (it > 0 ? (it - 1) : 0) * 512;
    const float* prn = part_r + it * 512;
    k_coil_fft_rows<<<dim3(8, 16, 4), 256, 0, stream>>>(
        p_prv, r, p_cur, pro, prn, it == 0 ? 1 : 0, csmh, twf, coil, part_p);
    k_fft_cols_mask<<<dim3(96, 16), 256, 0, stream>>>(coil, mask, twf, part_m);
    k_ifft_rows_upd<<<dim3(8, 64), 256, 0, stream>>>(
        coil, csmh, twf, p_cur, x, r, part_m, part_p,
        part_r + it * 512, part_r + (it + 1) * 512, lam,
        it == 10 ? (float*)d_out : (float*)nullptr);
  }
}